// Round 3
// baseline (5643.675 us; speedup 1.0000x reference)
//
#include <hip/hip_runtime.h>

// LSTM forward, persistent-kernel, R3:
//   R2 post-mortem: step = 6.8us but MFMA only ~0.2us. Costs: 128-serialized
//   RMW barrier (~3us), 5x chunked LDS pipeline each draining vmcnt(0)+barrier
//   (~2us), LDS round-trips. R3 removes all barriers from the compute phase:
//   - Weight B-fragments resident in VGPRs (80/wave), loaded once. No Bsm.
//   - A-fragments loaded straight from global into registers in MFMA layout
//     (x: plain L2 loads; H: relaxed agent-scope sc1 atomics). No LDS staging,
//     no per-chunk syncs; compiler interleaves MFMA with vmcnt(N).
//   - Distributed flag barrier: 1 sc1 store + 128 parallel line polls.
//   LDS holds only the 34KB K-split reduction buffer (3 syncthreads/step).

#define NB   128
#define SEQ  512
#define BATCH 64
#define DIM  256
#define HU   1024

typedef unsigned short u16;
typedef unsigned int   u32;
typedef unsigned long long u64;
typedef __attribute__((ext_vector_type(8))) short  short8;
typedef __attribute__((ext_vector_type(4))) float  f32x4;

__device__ __forceinline__ u16 f2bf(float x) {
  u32 u = __float_as_uint(x);
  u32 r = (u + 0x7FFFu + ((u >> 16) & 1u)) >> 16;   // RNE
  return (u16)r;
}
__device__ __forceinline__ float sigf(float x)  { return 1.0f / (1.0f + __expf(-x)); }
__device__ __forceinline__ float tanhfast(float x) { return 1.0f - 2.0f / (1.0f + __expf(2.0f * x)); }
__device__ __forceinline__ short8 mk8(u64 lo, u64 hi) {
  union { u64 d[2]; short8 s; } u; u.d[0] = lo; u.d[1] = hi; return u.s;
}
__device__ __forceinline__ short8 cv8(uint4 v) {
  union { uint4 d; short8 s; } u; u.d = v; return u.s;
}

// ---------------- prologue kernels ----------------

// 65536 threads: zero flags, Hbuf[0] = bf16(H0)
__global__ void k_prep(const float* __restrict__ H0, u16* __restrict__ Hbuf0,
                       u32* __restrict__ flags) {
  int i = blockIdx.x * 256 + threadIdx.x;
  if (i < 2048) flags[i] = 0u;
  Hbuf0[i] = f2bf(H0[i]);   // i < 65536 == BATCH*HU
}

// inputs fp32 (B,S,D) -> bf16 same layout; 2097152 threads, 4 elems each
__global__ void k_xconv(const float* __restrict__ in, u16* __restrict__ out) {
  int i = blockIdx.x * 256 + threadIdx.x;
  float4 v = ((const float4*)in)[i];
  ushort4 o;
  o.x = f2bf(v.x); o.y = f2bf(v.y); o.z = f2bf(v.z); o.w = f2bf(v.w);
  ((ushort4*)out)[i] = o;
}

// Build Wpack[j][nt(2)][kc(40)][lane(64)][8] bf16 : exact MFMA B-fragment order.
__global__ void k_pack(const float* __restrict__ Wxi, const float* __restrict__ Whi,
                       const float* __restrict__ Wxf, const float* __restrict__ Whf,
                       const float* __restrict__ Wxo, const float* __restrict__ Who,
                       const float* __restrict__ Wxc, const float* __restrict__ Whc,
                       u16* __restrict__ Wpack) {
  int tid  = blockIdx.x * 256 + threadIdx.x;   // < 128*2*40*64 = 655360
  int lane = tid & 63;
  int kc   = (tid >> 6) % 40;
  int nt   = ((tid >> 6) / 40) & 1;
  int j    = (tid >> 6) / 80;
  int col  = nt * 16 + (lane & 15);
  int gate = col >> 3;
  int h    = j * 8 + (col & 7);
  const float* Wx = (gate == 0) ? Wxi : (gate == 1) ? Wxf : (gate == 2) ? Wxo : Wxc;
  const float* Wh = (gate == 0) ? Whi : (gate == 1) ? Whf : (gate == 2) ? Who : Whc;
  int kbase = kc * 32 + ((lane >> 4) << 3);
  u16 tmp[8];
#pragma unroll
  for (int e = 0; e < 8; e++) {
    int k = kbase + e;
    float v = (k < DIM) ? Wx[k * HU + h] : Wh[(k - DIM) * HU + h];
    tmp[e] = f2bf(v);
  }
  *(uint4*)(Wpack + (size_t)tid * 8) = *(uint4*)tmp;
}

// pred[b,t] = bd + sum_j part[t][j][b];  32768 threads
__global__ void k_predsum(const float* __restrict__ part, const float* __restrict__ bd,
                          float* __restrict__ pred) {
  int i = blockIdx.x * 256 + threadIdx.x;
  int b = i & 63, t = i >> 6;
  float s = bd[0];
  const float* p0 = part + (size_t)t * NB * 64 + b;
#pragma unroll 8
  for (int jj = 0; jj < NB; jj++) s += p0[jj * 64];
  pred[b * SEQ + t] = s;
}

// ---------------- main persistent kernel ----------------

struct MainParams {
  const u16* __restrict__ xbf;     // (B,S,D) bf16
  const u16* __restrict__ Wpack;   // [NB][2][40][64][8] bf16
  u16* __restrict__ Hbuf;          // [2][B][HU] bf16 (double buffer)
  const float* __restrict__ C0;
  const float* __restrict__ Wd;
  const float* __restrict__ bi;
  const float* __restrict__ bfg;
  const float* __restrict__ bo;
  const float* __restrict__ bc;
  float* __restrict__ ppart;       // [SEQ][NB][64] pred partials
  float* __restrict__ Hf;          // [B][HU]
  float* __restrict__ Cf;          // [B][HU]
  u32* __restrict__ flags;         // [NB] stride-16 u32 (64B lines)
};

__global__ __launch_bounds__(256, 1) void lstm_main(MainParams p) {
  __shared__ float red[4 * 32 * 68];       // 34816 B K-split reduction

  const int tid  = threadIdx.x;
  const int wv   = tid >> 6, lane = tid & 63;
  const int j    = blockIdx.x;
  const int q8   = (lane >> 4) << 3;       // k sub-offset within a frag
  const int mrow = lane & 15;              // batch-row within 16-tile

  // resident weight B-fragments in VGPRs: slots = 2 x-chunks (kc=2wv+s) and
  // 8 H-chunks (kc=8+8wv+s), nt in {0,1}.  frag = Wpack[j][nt][kc][lane][8]
  short8 wx[2][2], wh[8][2];
  {
    const u16* base = p.Wpack + (size_t)j * 40960 + lane * 8;
#pragma unroll
    for (int s = 0; s < 2; s++)
#pragma unroll
      for (int nt = 0; nt < 2; nt++)
        wx[s][nt] = *(const short8*)(base + (nt * 40 + (2 * wv + s)) * 512);
#pragma unroll
    for (int s = 0; s < 8; s++)
#pragma unroll
      for (int nt = 0; nt < 2; nt++)
        wh[s][nt] = *(const short8*)(base + (nt * 40 + (8 + 8 * wv + s)) * 512);
  }

  // per-thread epilogue state: (b_, 2 h's)
  const int b_  = tid >> 2, hq = tid & 3;
  const int hg0 = j * 8 + hq * 2, hg1 = hg0 + 1;
  float c0v = p.C0[b_ * HU + hg0], c1v = p.C0[b_ * HU + hg1];
  const float wd0 = p.Wd[hg0], wd1 = p.Wd[hg1];
  const float bi0 = p.bi[hg0],  bi1 = p.bi[hg1];
  const float bf0 = p.bfg[hg0], bf1 = p.bfg[hg1];
  const float bo0 = p.bo[hg0],  bo1 = p.bo[hg1];
  const float bc0 = p.bc[hg0],  bc1 = p.bc[hg1];
  float h0f = 0.f, h1f = 0.f;

#pragma unroll 1
  for (int t = 0; t < SEQ; t++) {
    const int rb = t & 1;
    const u16* Hr = p.Hbuf + (size_t)rb * (BATCH * HU);
    u16*       Hw = p.Hbuf + (size_t)(rb ^ 1) * (BATCH * HU);

    // ---- issue all A-fragment loads (registers, MFMA layout) ----
    uint4 ax[2][4];                         // x frags: k = (2wv+s)*32 + q8
#pragma unroll
    for (int s = 0; s < 2; s++)
#pragma unroll
      for (int mt = 0; mt < 4; mt++) {
        int m = mt * 16 + mrow;
        ax[s][mt] = *(const uint4*)(p.xbf + ((size_t)(m * SEQ + t)) * DIM
                                    + (2 * wv + s) * 32 + q8);
      }
    u64 ah[8][4][2];                        // H frags: kH = 256*wv + 32*s + q8
#pragma unroll
    for (int s = 0; s < 8; s++)
#pragma unroll
      for (int mt = 0; mt < 4; mt++) {
        int m = mt * 16 + mrow;
        const u64* hp = (const u64*)(Hr + m * HU + 256 * wv + 32 * s + q8);
        ah[s][mt][0] = __hip_atomic_load(hp,     __ATOMIC_RELAXED, __HIP_MEMORY_SCOPE_AGENT);
        ah[s][mt][1] = __hip_atomic_load(hp + 1, __ATOMIC_RELAXED, __HIP_MEMORY_SCOPE_AGENT);
      }

    // ---- MFMA, consume in issue order (compiler inserts fine vmcnt) ----
    f32x4 acc[4][2];
#pragma unroll
    for (int mt = 0; mt < 4; mt++)
#pragma unroll
      for (int nt = 0; nt < 2; nt++) acc[mt][nt] = (f32x4){0.f, 0.f, 0.f, 0.f};
#pragma unroll
    for (int s = 0; s < 2; s++)
#pragma unroll
      for (int mt = 0; mt < 4; mt++) {
        short8 af = cv8(ax[s][mt]);
        acc[mt][0] = __builtin_amdgcn_mfma_f32_16x16x32_bf16(af, wx[s][0], acc[mt][0], 0, 0, 0);
        acc[mt][1] = __builtin_amdgcn_mfma_f32_16x16x32_bf16(af, wx[s][1], acc[mt][1], 0, 0, 0);
      }
#pragma unroll
    for (int s = 0; s < 8; s++)
#pragma unroll
      for (int mt = 0; mt < 4; mt++) {
        short8 af = mk8(ah[s][mt][0], ah[s][mt][1]);
        acc[mt][0] = __builtin_amdgcn_mfma_f32_16x16x32_bf16(af, wh[s][0], acc[mt][0], 0, 0, 0);
        acc[mt][1] = __builtin_amdgcn_mfma_f32_16x16x32_bf16(af, wh[s][1], acc[mt][1], 0, 0, 0);
      }

    // ---- K-split reduction across waves: red[wv][col(32)][68] ----
    {
      const int cb = lane & 15, q = lane >> 4;
#pragma unroll
      for (int mt = 0; mt < 4; mt++)
#pragma unroll
        for (int nt = 0; nt < 2; nt++) {
          int addr = (wv * 32 + nt * 16 + cb) * 68 + mt * 16 + q * 4;
          *(f32x4*)(red + addr) = acc[mt][nt];
        }
    }
    __syncthreads();

    // ---- epilogue: thread owns (b_, hg0, hg1) ----
    float gv[8];
#pragma unroll
    for (int gg = 0; gg < 4; gg++)
#pragma unroll
      for (int e = 0; e < 2; e++) {
        int col = gg * 8 + hq * 2 + e;
        gv[gg * 2 + e] = red[(0 * 32 + col) * 68 + b_] + red[(1 * 32 + col) * 68 + b_]
                       + red[(2 * 32 + col) * 68 + b_] + red[(3 * 32 + col) * 68 + b_];
      }
    float i0 = sigf(gv[0] + bi0), i1 = sigf(gv[1] + bi1);
    float f0 = sigf(gv[2] + bf0), f1 = sigf(gv[3] + bf1);
    float o0 = sigf(gv[4] + bo0), o1 = sigf(gv[5] + bo1);
    float ct0 = tanhfast(gv[6] + bc0), ct1 = tanhfast(gv[7] + bc1);
    c0v = f0 * c0v + i0 * ct0;  c1v = f1 * c1v + i1 * ct1;
    h0f = o0 * tanhfast(c0v);   h1f = o1 * tanhfast(c1v);

    // pred partial: reduce 4 threads sharing b_, plain store to ws
    float pr = h0f * wd0 + h1f * wd1;
    pr += __shfl_xor(pr, 1);
    pr += __shfl_xor(pr, 2);
    if ((lane & 3) == 0) p.ppart[(size_t)t * NB * 64 + j * 64 + b_] = pr;

    // publish H_t (sc1 store to LLC)
    u32 hv = (u32)f2bf(h0f) | ((u32)f2bf(h1f) << 16);
    __hip_atomic_store((u32*)(Hw + b_ * HU + hg0), hv,
                       __ATOMIC_RELAXED, __HIP_MEMORY_SCOPE_AGENT);

    // ---- distributed flag barrier ----
    // __syncthreads drains every thread's vmcnt -> all sc1 H-stores are at the
    // LLC before tid0's flag store is issued (same ordering R2 validated).
    __syncthreads();
    if (tid == 0)
      __hip_atomic_store(p.flags + j * 16, (u32)(t + 1),
                         __ATOMIC_RELAXED, __HIP_MEMORY_SCOPE_AGENT);
    if (tid < NB) {
      const u32* f = p.flags + tid * 16;
      while (__hip_atomic_load(f, __ATOMIC_RELAXED, __HIP_MEMORY_SCOPE_AGENT) < (u32)(t + 1))
        __builtin_amdgcn_s_sleep(1);
    }
    __syncthreads();
  }

  // finals
  p.Hf[b_ * HU + hg0] = h0f; p.Hf[b_ * HU + hg1] = h1f;
  p.Cf[b_ * HU + hg0] = c0v; p.Cf[b_ * HU + hg1] = c1v;
}

// ---------------- launch ----------------

extern "C" void kernel_launch(void* const* d_in, const int* in_sizes, int n_in,
                              void* d_out, int out_size, void* d_ws, size_t ws_size,
                              hipStream_t stream) {
  const float* inputs = (const float*)d_in[0];
  const float* H0  = (const float*)d_in[1];
  const float* C0  = (const float*)d_in[2];
  const float* Wxi = (const float*)d_in[3];
  const float* Whi = (const float*)d_in[4];
  const float* bi  = (const float*)d_in[5];
  const float* Wxf = (const float*)d_in[6];
  const float* Whf = (const float*)d_in[7];
  const float* bf_ = (const float*)d_in[8];
  const float* Wxo = (const float*)d_in[9];
  const float* Who = (const float*)d_in[10];
  const float* bo  = (const float*)d_in[11];
  const float* Wxc = (const float*)d_in[12];
  const float* Whc = (const float*)d_in[13];
  const float* bc  = (const float*)d_in[14];
  const float* Wd  = (const float*)d_in[15];
  const float* bd  = (const float*)d_in[16];

  char* ws = (char*)d_ws;
  u32*   flags = (u32*)ws;                                      // 8192 B
  u16*   Wpack = (u16*)(ws + 8192);                             // 10485760 B
  u16*   xbf   = (u16*)(ws + 8192 + 10485760);                  // 16777216 B
  u16*   Hbuf  = (u16*)(ws + 8192 + 10485760 + 16777216);       // 262144 B
  float* ppart = (float*)(ws + 8192 + 10485760 + 16777216 + 262144); // 16777216 B

  float* pred = (float*)d_out;
  float* Hf   = pred + BATCH * SEQ;
  float* Cf   = Hf + BATCH * HU;

  k_prep<<<256, 256, 0, stream>>>(H0, Hbuf, flags);
  k_xconv<<<8192, 256, 0, stream>>>(inputs, xbf);
  k_pack<<<2560, 256, 0, stream>>>(Wxi, Whi, Wxf, Whf, Wxo, Who, Wxc, Whc, Wpack);

  MainParams prm{xbf, Wpack, Hbuf, C0, Wd, bi, bf_, bo, bc, ppart, Hf, Cf, flags};
  lstm_main<<<dim3(NB), dim3(256), 0, stream>>>(prm);

  k_predsum<<<128, 256, 0, stream>>>(ppart, bd, pred);
}